// Round 1
// baseline (297.452 us; speedup 1.0000x reference)
//
#include <hip/hip_runtime.h>
#include <math.h>

#define N_NODES 32768
#define HC 256
#define NPG 512
#define NGRAPH 64
#define KKEEP 256
#define CAP 64

// ---------------- GEMM: h = x @ W, fused a_src/a_dst ----------------
// grid: N/64 blocks of 256 threads. Tile 64 rows x 256 cols, K-chunks of 32.
__global__ __launch_bounds__(256) void k_gemm(
    const float* __restrict__ x, const float* __restrict__ W,
    const float* __restrict__ attS, const float* __restrict__ attD,
    float* __restrict__ h, float* __restrict__ a_src, float* __restrict__ a_dst) {
  __shared__ float xs[64][36];   // stride 36: 16B-aligned float4 reads, broadcast access
  __shared__ float ws[32][256];
  const int t = threadIdx.x;
  const int ty = t >> 6;         // wave id 0..3 -> row quarter
  const int tx = t & 63;         // lane -> 4-col group
  const int row0 = blockIdx.x * 64;
  const int c0 = tx * 4;
  float4 acc[16];
#pragma unroll
  for (int i = 0; i < 16; i++) acc[i] = make_float4(0.f, 0.f, 0.f, 0.f);

  for (int k0 = 0; k0 < 256; k0 += 32) {
    {
      int r = t >> 3, f = t & 7;
      const float4* s1 = (const float4*)&x[(size_t)(row0 + r) * 256 + k0];
      *(float4*)&xs[r][f * 4] = s1[f];
      const float4* s2 = (const float4*)&x[(size_t)(row0 + r + 32) * 256 + k0];
      *(float4*)&xs[r + 32][f * 4] = s2[f];
    }
#pragma unroll
    for (int m = 0; m < 8; m++) {
      int idx = m * 256 + t;
      int kr = idx >> 6, f4 = (idx & 63) * 4;
      *(float4*)&ws[kr][f4] = *(const float4*)&W[(size_t)(k0 + kr) * 256 + f4];
    }
    __syncthreads();
#pragma unroll
    for (int kk = 0; kk < 32; kk += 4) {
      float4 wv0 = *(float4*)&ws[kk + 0][c0];
      float4 wv1 = *(float4*)&ws[kk + 1][c0];
      float4 wv2 = *(float4*)&ws[kk + 2][c0];
      float4 wv3 = *(float4*)&ws[kk + 3][c0];
#pragma unroll
      for (int i = 0; i < 16; i++) {
        float4 xv = *(float4*)&xs[ty * 16 + i][kk];
        float4 a = acc[i];
        a.x = fmaf(xv.w, wv3.x, fmaf(xv.z, wv2.x, fmaf(xv.y, wv1.x, fmaf(xv.x, wv0.x, a.x))));
        a.y = fmaf(xv.w, wv3.y, fmaf(xv.z, wv2.y, fmaf(xv.y, wv1.y, fmaf(xv.x, wv0.y, a.y))));
        a.z = fmaf(xv.w, wv3.z, fmaf(xv.z, wv2.z, fmaf(xv.y, wv1.z, fmaf(xv.x, wv0.z, a.z))));
        a.w = fmaf(xv.w, wv3.w, fmaf(xv.z, wv2.w, fmaf(xv.y, wv1.w, fmaf(xv.x, wv0.w, a.w))));
        acc[i] = a;
      }
    }
    __syncthreads();
  }
  // epilogue: store h rows + attention dot products (reduce across 16 lanes/head)
  const float4 aS = *(const float4*)&attS[c0];
  const float4 aD = *(const float4*)&attD[c0];
  const int head = tx >> 4;
#pragma unroll
  for (int i = 0; i < 16; i++) {
    int r = row0 + ty * 16 + i;
    *(float4*)&h[(size_t)r * 256 + c0] = acc[i];
    float ps = acc[i].x * aS.x + acc[i].y * aS.y + acc[i].z * aS.z + acc[i].w * aS.w;
    float pd = acc[i].x * aD.x + acc[i].y * aD.y + acc[i].z * aD.z + acc[i].w * aD.w;
#pragma unroll
    for (int d = 1; d < 16; d <<= 1) {
      ps += __shfl_xor(ps, d, 16);
      pd += __shfl_xor(pd, d, 16);
    }
    if ((tx & 15) == 0) {
      a_src[r * 4 + head] = ps;
      a_dst[r * 4 + head] = pd;
    }
  }
}

// ---------------- edge bucketing by dst ----------------
__global__ void k_hist(const int* __restrict__ ei, int E, int* __restrict__ cnt,
                       int* __restrict__ nbr) {
  int e = blockIdx.x * 256 + threadIdx.x;
  if (e < E) {
    int s = ei[e];
    int d = ei[E + e];
    int slot = atomicAdd(&cnt[d], 1);
    if (slot < CAP) nbr[(size_t)d * CAP + slot] = s;
  }
}

// ---------------- per-node online-softmax aggregation ----------------
// one wave per node; lane i handles channels 4i..4i+3; head = lane>>4
__global__ __launch_bounds__(256) void k_agg(
    const float* __restrict__ h, const float* __restrict__ a_src,
    const float* __restrict__ a_dst, const int* __restrict__ cnt,
    const int* __restrict__ nbr, const float* __restrict__ bias,
    float* __restrict__ feat) {
  const int lane = threadIdx.x & 63;
  const int node = blockIdx.x * 4 + (threadIdx.x >> 6);
  const int head = lane >> 4;
  const int c0 = lane * 4;
  const float ad = a_dst[node * 4 + head];
  int n = cnt[node];
  if (n > CAP) n = CAP;
  float m = -1e30f, l = 0.f;
  float4 acc = make_float4(0.f, 0.f, 0.f, 0.f);
  for (int j = 0; j <= n; j++) {           // j==n -> self loop
    int src = (j < n) ? nbr[(size_t)node * CAP + j] : node;
    float e = a_src[src * 4 + head] + ad;
    e = (e > 0.f) ? e : 0.2f * e;
    float nm = fmaxf(m, e);
    float sc = __expf(m - nm);
    float p = __expf(e - nm);
    l = l * sc + p;
    float4 hv = *(const float4*)&h[(size_t)src * 256 + c0];
    acc.x = fmaf(p, hv.x, acc.x * sc);
    acc.y = fmaf(p, hv.y, acc.y * sc);
    acc.z = fmaf(p, hv.z, acc.z * sc);
    acc.w = fmaf(p, hv.w, acc.w * sc);
    m = nm;
  }
  const float inv = 1.f / (l + 1e-16f);
  const float4 b4 = *(const float4*)&bias[c0];
  float4 o;
  o.x = fmaxf(fmaf(acc.x, inv, b4.x), 0.f);
  o.y = fmaxf(fmaf(acc.y, inv, b4.y), 0.f);
  o.z = fmaxf(fmaf(acc.z, inv, b4.z), 0.f);
  o.w = fmaxf(fmaf(acc.w, inv, b4.w), 0.f);
  *(float4*)&feat[(size_t)node * 256 + c0] = o;
}

// ---------------- BN stats: partial sums (double accumulators) ----------------
__global__ __launch_bounds__(256) void k_bn_partial(const float* __restrict__ feat,
                                                    double* __restrict__ psum,
                                                    double* __restrict__ psq) {
  const int c = threadIdx.x;
  const int r0 = blockIdx.x * 128;
  double s = 0.0, q = 0.0;
  for (int i = 0; i < 128; i++) {
    double v = (double)feat[(size_t)(r0 + i) * 256 + c];
    s += v;
    q += v * v;
  }
  psum[blockIdx.x * 256 + c] = s;
  psq[blockIdx.x * 256 + c] = q;
}

__global__ __launch_bounds__(256) void k_bn_final(
    const double* __restrict__ psum, const double* __restrict__ psq,
    const float* __restrict__ gam, const float* __restrict__ bet,
    const float* __restrict__ pw, float* __restrict__ cA, float* __restrict__ cB,
    float* __restrict__ pwn) {
  __shared__ double wsq[256];
  const int c = threadIdx.x;
  double s = 0.0, q = 0.0;
  for (int i = 0; i < 256; i++) {
    s += psum[i * 256 + c];
    q += psq[i * 256 + c];
  }
  double mean = s / (double)N_NODES;
  double var = q / (double)N_NODES - mean * mean;
  double a = (double)gam[c] / sqrt(var + 1e-5);
  cA[c] = (float)a;
  cB[c] = (float)((double)bet[c] - mean * a);
  double w = (double)pw[c];
  wsq[c] = w * w;
  __syncthreads();
  if (c == 0) {
    double nn = 0.0;
    for (int i = 0; i < 256; i++) nn += wsq[i];
    wsq[0] = sqrt(nn);
  }
  __syncthreads();
  pwn[c] = (float)((double)pw[c] / wsq[0]);
}

// ---------------- score: one wave per node ----------------
__global__ __launch_bounds__(256) void k_score(
    const float* __restrict__ feat, const float* __restrict__ cA,
    const float* __restrict__ cB, const float* __restrict__ pwn,
    float* __restrict__ score) {
  const int lane = threadIdx.x & 63;
  const int node = blockIdx.x * 4 + (threadIdx.x >> 6);
  const int c0 = lane * 4;
  float4 f = *(const float4*)&feat[(size_t)node * 256 + c0];
  float4 a = *(const float4*)&cA[c0];
  float4 b = *(const float4*)&cB[c0];
  float4 w = *(const float4*)&pwn[c0];
  float p = fmaf(f.x, a.x, b.x) * w.x + fmaf(f.y, a.y, b.y) * w.y +
            fmaf(f.z, a.z, b.z) * w.z + fmaf(f.w, a.w, b.w) * w.w;
#pragma unroll
  for (int d = 1; d < 64; d <<= 1) p += __shfl_xor(p, d, 64);
  if (lane == 0) score[node] = p;
}

// ---------------- topk + gather, one block per graph ----------------
__global__ __launch_bounds__(512) void k_topk(
    const float* __restrict__ score, const float* __restrict__ feat,
    const float* __restrict__ cA, const float* __restrict__ cB,
    float* __restrict__ out) {
  __shared__ float ss[NPG];
  __shared__ int sel[KKEEP];
  __shared__ float gate[KKEEP];
  const int g = blockIdx.x;
  const int t = threadIdx.x;
  float s = score[g * NPG + t];
  ss[t] = s;
  __syncthreads();
  int rank = 0;
  for (int j = 0; j < NPG; j++) {
    float sj = ss[j];
    rank += (sj > s || (sj == s && j < t)) ? 1 : 0;
  }
  if (rank < KKEEP) {
    sel[rank] = t;
    gate[rank] = tanhf(s);
  }
  __syncthreads();
  for (int idx = t; idx < KKEEP * 64; idx += 512) {
    int r = idx >> 6;
    int c4 = (idx & 63) * 4;
    int node = g * NPG + sel[r];
    float4 f = *(const float4*)&feat[(size_t)node * 256 + c4];
    float4 a = *(const float4*)&cA[c4];
    float4 b = *(const float4*)&cB[c4];
    float tg = gate[r];
    float4 o;
    o.x = fmaf(f.x, a.x, b.x) * tg;
    o.y = fmaf(f.y, a.y, b.y) * tg;
    o.z = fmaf(f.z, a.z, b.z) * tg;
    o.w = fmaf(f.w, a.w, b.w) * tg;
    *(float4*)&out[(size_t)(g * KKEEP + r) * 256 + c4] = o;
  }
}

extern "C" void kernel_launch(void* const* d_in, const int* in_sizes, int n_in,
                              void* d_out, int out_size, void* d_ws, size_t ws_size,
                              hipStream_t stream) {
  const float* x    = (const float*)d_in[0];
  const int*   ei   = (const int*)d_in[1];
  const float* W    = (const float*)d_in[2];
  const float* attS = (const float*)d_in[3];
  const float* attD = (const float*)d_in[4];
  const float* bias = (const float*)d_in[5];
  const float* gam  = (const float*)d_in[6];
  const float* bet  = (const float*)d_in[7];
  const float* pw   = (const float*)d_in[8];
  float* out = (float*)d_out;
  const int E = in_sizes[1] / 2;

  char* p = (char*)d_ws;
  float* h     = (float*)p; p += (size_t)N_NODES * 256 * 4;
  float* feat  = (float*)p; p += (size_t)N_NODES * 256 * 4;
  float* a_src = (float*)p; p += (size_t)N_NODES * 4 * 4;
  float* a_dst = (float*)p; p += (size_t)N_NODES * 4 * 4;
  float* score = (float*)p; p += (size_t)N_NODES * 4;
  double* psum = (double*)p; p += (size_t)256 * 256 * 8;
  double* psq  = (double*)p; p += (size_t)256 * 256 * 8;
  float* cA    = (float*)p; p += 256 * 4;
  float* cB    = (float*)p; p += 256 * 4;
  float* pwn   = (float*)p; p += 256 * 4;
  int* cnt     = (int*)p;   p += (size_t)N_NODES * 4;
  int* nbr     = (int*)p;   p += (size_t)N_NODES * CAP * 4;

  hipMemsetAsync(cnt, 0, (size_t)N_NODES * 4, stream);
  k_hist<<<(E + 255) / 256, 256, 0, stream>>>(ei, E, cnt, nbr);
  k_gemm<<<N_NODES / 64, 256, 0, stream>>>(x, W, attS, attD, h, a_src, a_dst);
  k_agg<<<N_NODES / 4, 256, 0, stream>>>(h, a_src, a_dst, cnt, nbr, bias, feat);
  k_bn_partial<<<256, 256, 0, stream>>>(feat, psum, psq);
  k_bn_final<<<1, 256, 0, stream>>>(psum, psq, gam, bet, pw, cA, cB, pwn);
  k_score<<<N_NODES / 4, 256, 0, stream>>>(feat, cA, cB, pwn, score);
  k_topk<<<NGRAPH, 512, 0, stream>>>(score, feat, cA, cB, out);
}